// Round 2
// baseline (31640.140 us; speedup 1.0000x reference)
//
#include <hip/hip_runtime.h>
#include <hip/hip_fp16.h>

#define HD 512
#define Bsz 64
#define Tlen 512
#define BW 16      // batch per group
#define RS 16      // weight rows per slice
#define NSLICE 32  // WGs per group
#define NGROUP 4

typedef _Float16 f16x8 __attribute__((ext_vector_type(8)));
typedef float f32x4 __attribute__((ext_vector_type(4)));

__device__ __forceinline__ f16x8 u4f16(uint4 u) { return __builtin_bit_cast(f16x8, u); }

__device__ __forceinline__ f16x8 load_x_frag(const float* __restrict__ p) {
    float4 u = *(const float4*)p;
    float4 v = *(const float4*)(p + 4);
    f16x8 r;
    r[0] = (_Float16)u.x; r[1] = (_Float16)u.y; r[2] = (_Float16)u.z; r[3] = (_Float16)u.w;
    r[4] = (_Float16)v.x; r[5] = (_Float16)v.y; r[6] = (_Float16)v.z; r[7] = (_Float16)v.w;
    return r;
}

// wp layout: uint4[ ((s*4 + mat)*16 + ks)*64 + lane ]
//   mat: 0=Wih L0, 1=Whh L0, 2=Wih L1, 3=Whh L1
//   lane holds W[row = s*16 + (lane&15)][k = ks*32 + (lane>>4)*8 + j], j=0..7 (f16)
__global__ __launch_bounds__(256) void pack_w(const float* __restrict__ Wih,
                                              const float* __restrict__ Whh,
                                              uint4* __restrict__ wp) {
    int tid = blockIdx.x * 256 + threadIdx.x;  // 131072 total
    int l   = tid & 63;
    int ks  = (tid >> 6) & 15;
    int mat = (tid >> 10) & 3;
    int s   = tid >> 12;
    int row = s * RS + (l & 15);
    int kb  = ks * 32 + (l >> 4) * 8;
    const float* W = (mat == 0) ? Wih
                   : (mat == 1) ? Whh
                   : (mat == 2) ? (Wih + HD * HD)
                                : (Whh + HD * HD);
    const float* p = W + (size_t)row * HD + kb;
    union { uint4 u; _Float16 h[8]; } v;
#pragma unroll
    for (int r = 0; r < 8; ++r) v.h[r] = (_Float16)p[r];
    wp[tid] = v.u;
}

// H0/H1: [2 slots][64][512] f16. Slot 1 = "prev" at t=0 -> init from h0.
__global__ __launch_bounds__(512) void init_h(const float* __restrict__ h0in,
                                              _Float16* __restrict__ H0,
                                              _Float16* __restrict__ H1) {
    int tid = blockIdx.x * 512 + threadIdx.x;  // 65536
    _Float16 v = (_Float16)h0in[tid];
    if (tid < 32768) H0[32768 + tid] = v;
    else             H1[32768 + (tid - 32768)] = v;
}

__global__ __launch_bounds__(512) void rnn_chain(const float* __restrict__ x,
                                                 const float* __restrict__ bih,
                                                 const float* __restrict__ bhh,
                                                 const uint4* __restrict__ wp,
                                                 _Float16* __restrict__ H0,
                                                 _Float16* __restrict__ H1,
                                                 unsigned* __restrict__ cnt,
                                                 float* __restrict__ out) {
    __shared__ float part[8 * 16 * 17];  // [wave][m(batch)][n(row), padded]

    const int g = blockIdx.x >> 5;   // group
    const int s = blockIdx.x & 31;   // slice
    const int tid = threadIdx.x;
    const int w = tid >> 6;
    const int l = tid & 63;
    const int q = l >> 4;
    const bool hhw = (w >= 4);       // waves 4-7: hh matvec; 0-3: ih
    const int kc = (w & 3) * 128;    // this wave's K chunk

    const uint4* bf0 = wp + (((size_t)(s * 4 + (hhw ? 1 : 0)) * 16 + (w & 3) * 4) * 64 + l);
    const uint4* bf1 = wp + (((size_t)(s * 4 + 2 + (hhw ? 1 : 0)) * 16 + (w & 3) * 4) * 64 + l);

    const int bglob = g * BW + (l & 15);                       // A-row batch index
    const float* xbase = x + (size_t)bglob * (Tlen * HD) + kc + q * 8;

    // epilogue assignment (threads 0..255): m = batch-in-group, n = row-in-slice
    const int em = tid >> 4, en = tid & 15;
    float b0 = 0.f, b1 = 0.f;
    if (tid < 256) {
        int rowg = s * RS + en;
        b0 = bih[rowg] + bhh[rowg];
        b1 = bih[HD + rowg] + bhh[HD + rowg];
    }
    const int hidx = (g * BW + em) * HD + s * RS + en;           // into [64][512]
    float* outb = out + (size_t)(g * BW + em) * Tlen * HD + s * RS + en;
    float* hf = out + (size_t)Bsz * Tlen * HD;

    unsigned* c = cnt + g * 1024;  // one counter per half-step

    f16x8 xa[4];
    if (!hhw) {
#pragma unroll
        for (int i = 0; i < 4; ++i) xa[i] = load_x_frag(xbase + i * 32);
    }

    for (int t = 0; t < Tlen; ++t) {
        const int cur = t & 1, prev = cur ^ 1;
        const _Float16* h0p = H0 + prev * 32768;
        const _Float16* h0c = H0 + cur * 32768;
        const _Float16* h1p = H1 + prev * 32768;

        // ================= layer 0 =================
        f32x4 acc = {0.f, 0.f, 0.f, 0.f};
        if (!hhw) {
#pragma unroll
            for (int i = 0; i < 4; ++i)
                acc = __builtin_amdgcn_mfma_f32_16x16x32_f16(xa[i], u4f16(bf0[i * 64]), acc, 0, 0, 0);
        } else {
            const uint4* ap = (const uint4*)(h0p + (size_t)bglob * HD + kc + q * 8);
#pragma unroll
            for (int i = 0; i < 4; ++i)
                acc = __builtin_amdgcn_mfma_f32_16x16x32_f16(u4f16(ap[i * 4]), u4f16(bf0[i * 64]), acc, 0, 0, 0);
        }
#pragma unroll
        for (int r = 0; r < 4; ++r) part[(w * 16 + q * 4 + r) * 17 + (l & 15)] = acc[r];
        __syncthreads();
        if (tid < 256) {
            float sum = b0;
#pragma unroll
            for (int ww = 0; ww < 8; ++ww) sum += part[(ww * 16 + em) * 17 + en];
            float h0v = tanhf(sum);
            (H0 + cur * 32768)[hidx] = (_Float16)h0v;
            if (t == Tlen - 1) hf[hidx] = h0v;
        }
        // ---- group barrier #1 (h0_t ready) ----
        __threadfence();
        __syncthreads();
        if (tid == 0) {
            unsigned* cc = c + t * 2;
            __hip_atomic_fetch_add(cc, 1u, __ATOMIC_RELEASE, __HIP_MEMORY_SCOPE_AGENT);
            while (__hip_atomic_load(cc, __ATOMIC_ACQUIRE, __HIP_MEMORY_SCOPE_AGENT) < NSLICE)
                __builtin_amdgcn_s_sleep(2);
        }
        __syncthreads();
        (void)__hip_atomic_load(c + t * 2, __ATOMIC_ACQUIRE, __HIP_MEMORY_SCOPE_AGENT);

        // ================= layer 1 =================
        f32x4 acc1 = {0.f, 0.f, 0.f, 0.f};
        {
            const _Float16* ain = hhw ? h1p : h0c;
            const uint4* ap = (const uint4*)(ain + (size_t)bglob * HD + kc + q * 8);
#pragma unroll
            for (int i = 0; i < 4; ++i)
                acc1 = __builtin_amdgcn_mfma_f32_16x16x32_f16(u4f16(ap[i * 4]), u4f16(bf1[i * 64]), acc1, 0, 0, 0);
        }
#pragma unroll
        for (int r = 0; r < 4; ++r) part[(w * 16 + q * 4 + r) * 17 + (l & 15)] = acc1[r];
        __syncthreads();
        if (tid < 256) {
            float sum = b1;
#pragma unroll
            for (int ww = 0; ww < 8; ++ww) sum += part[(ww * 16 + em) * 17 + en];
            float h1v = tanhf(sum);
            (H1 + cur * 32768)[hidx] = (_Float16)h1v;
            outb[(size_t)t * HD] = h1v;
            if (t == Tlen - 1) hf[32768 + hidx] = h1v;
        }
        // ---- group barrier #2 (h1_t ready), x prefetch overlapped ----
        __threadfence();
        __syncthreads();
        if (tid == 0)
            __hip_atomic_fetch_add(c + t * 2 + 1, 1u, __ATOMIC_RELEASE, __HIP_MEMORY_SCOPE_AGENT);
        if (!hhw && t + 1 < Tlen) {
            const float* p = xbase + (size_t)(t + 1) * HD;
#pragma unroll
            for (int i = 0; i < 4; ++i) xa[i] = load_x_frag(p + i * 32);
        }
        if (tid == 0) {
            unsigned* cc = c + t * 2 + 1;
            while (__hip_atomic_load(cc, __ATOMIC_ACQUIRE, __HIP_MEMORY_SCOPE_AGENT) < NSLICE)
                __builtin_amdgcn_s_sleep(2);
        }
        __syncthreads();
        (void)__hip_atomic_load(c + t * 2 + 1, __ATOMIC_ACQUIRE, __HIP_MEMORY_SCOPE_AGENT);
    }
}

extern "C" void kernel_launch(void* const* d_in, const int* in_sizes, int n_in,
                              void* d_out, int out_size, void* d_ws, size_t ws_size,
                              hipStream_t stream) {
    const float* x   = (const float*)d_in[0];
    const float* h0  = (const float*)d_in[1];
    const float* Wih = (const float*)d_in[2];
    const float* bih = (const float*)d_in[3];
    const float* Whh = (const float*)d_in[4];
    const float* bhh = (const float*)d_in[5];
    float* out = (float*)d_out;

    char* ws = (char*)d_ws;
    uint4*     wp  = (uint4*)ws;                                // 2 MB
    _Float16*  H0  = (_Float16*)(ws + (2u << 20));              // 128 KB (2 slots)
    _Float16*  H1  = (_Float16*)(ws + (2u << 20) + (128u << 10));
    unsigned*  cnt = (unsigned*)(ws + (2u << 20) + (256u << 10)); // 16 KB

    hipMemsetAsync(cnt, 0, NGROUP * 1024 * sizeof(unsigned), stream);
    pack_w<<<dim3(512), dim3(256), 0, stream>>>(Wih, Whh, wp);
    init_h<<<dim3(128), dim3(512), 0, stream>>>(h0, H0, H1);
    rnn_chain<<<dim3(NGROUP * NSLICE), dim3(512), 0, stream>>>(x, bih, bhh, wp, H0, H1, cnt, out);
}

// Round 4
// 2659.206 us; speedup vs baseline: 11.8983x; 11.8983x over previous
//
#include <hip/hip_runtime.h>
#include <hip/hip_fp16.h>

#define HD 512
#define Bsz 64
#define Tlen 512
#define GB 4
#define RING 16

typedef _Float16 h2v __attribute__((ext_vector_type(2)));
typedef unsigned long long ull;

__device__ __forceinline__ float dot2acc(unsigned a, unsigned b, float c) {
    return __builtin_amdgcn_fdot2(__builtin_bit_cast(h2v, a),
                                  __builtin_bit_cast(h2v, b), c, false);
}

// All cross-WG traffic: RELAXED agent-scope atomics only (no acquire/release,
// no threadfence — those emit L2 cache-maintenance on gfx950, round-2 lesson).
__device__ __forceinline__ void spin_ge8(unsigned* p) {
    while (__hip_atomic_load(p, __ATOMIC_RELAXED, __HIP_MEMORY_SCOPE_AGENT) < 8u)
        __builtin_amdgcn_s_sleep(1);
}
__device__ __forceinline__ ull ring_ld(const _Float16* p) {
    return __hip_atomic_load((const ull*)p, __ATOMIC_RELAXED, __HIP_MEMORY_SCOPE_AGENT);
}
__device__ __forceinline__ void ring_st(_Float16* p, ull v) {
    __hip_atomic_store((ull*)p, v, __ATOMIC_RELAXED, __HIP_MEMORY_SCOPE_AGENT);
}
__device__ __forceinline__ void cvt4s(_Float16* d, float4 v) {
    union { ull u; _Float16 h[4]; } t;
    t.h[0] = (_Float16)v.x; t.h[1] = (_Float16)v.y;
    t.h[2] = (_Float16)v.z; t.h[3] = (_Float16)v.w;
    *(ull*)d = t.u;
}

// Grid: 256 WGs = (slice sl 0..15) x (group g 0..15); sl = l*8 + rb.
// WG owns rows [rb*64, rb*64+64) of layer l, batches [g*4, g*4+4).
// Weights live in REGISTERS: thread (rh,kq,rq) holds W[rows rq+16*(2rh+ri)]
// [k8 = kq+16i], ri in 0..1, i in 0..3, for both Wih and Whh (16 uint4).
__global__ __launch_bounds__(512, 1) void rnn_chain(
    const float* __restrict__ x, const float* __restrict__ h0in,
    const float* __restrict__ Wih, const float* __restrict__ bih,
    const float* __restrict__ Whh, const float* __restrict__ bhh,
    _Float16* __restrict__ H0r, _Float16* __restrict__ H1r,
    unsigned* __restrict__ c0, unsigned* __restrict__ c1,
    float* __restrict__ out)
{
    __shared__ _Float16 inb[128 * GB * 8] __attribute__((aligned(16)));
    __shared__ float    part[256 * 17];
    __shared__ _Float16 hout[256] __attribute__((aligned(16)));

    const int bid = blockIdx.x;
    const int g   = bid & 15;
    const int sl  = bid >> 4;
    const int l   = sl >> 3;
    const int rb  = sl & 7;
    const int tid = threadIdx.x;
    const int rh = tid >> 8, kq = (tid >> 4) & 15, rq = tid & 15;

    uint4 wreg[16];
    {
        const float* WI = Wih + (size_t)l * HD * HD;
        const float* WH = Whh + (size_t)l * HD * HD;
#pragma unroll
        for (int ph = 0; ph < 2; ++ph) {
            const float* W = ph ? WH : WI;
#pragma unroll
            for (int i = 0; i < 4; ++i)
#pragma unroll
                for (int ri = 0; ri < 2; ++ri) {
                    const int row = rb * 64 + rq + 16 * (2 * rh + ri);
                    const float* p = W + (size_t)row * HD + (kq + 16 * i) * 8;
                    union { uint4 u; _Float16 h[8]; } v;
#pragma unroll
                    for (int e = 0; e < 8; ++e) v.h[e] = (_Float16)p[e];
                    wreg[ph * 8 + i * 2 + ri] = v.u;
                }
        }
    }

    float bias = 0.f;
    if (tid < 256) {
        const int rowg = rb * 64 + (tid & 63);
        bias = bih[l * HD + rowg] + bhh[l * HD + rowg];
    }

    unsigned* cg0 = c0 + g * Tlen;
    unsigned* cg1 = c1 + g * Tlen;
    unsigned* cown = l ? cg1 : cg0;
    _Float16* ringo = l ? H1r : H0r;

    const int bb = tid >> 7;      // staging role: batch-in-group
    const int k4 = tid & 127;     // staging role: 4-f16 chunk
    const int bglobS = g * GB + bb;

    for (int t = 0; t < Tlen; ++t) {
        const int slot = t & (RING - 1);
        float acc[2][4] = {{0, 0, 0, 0}, {0, 0, 0, 0}};

        // ---------- phase A staging (early input) ----------
        if (l == 0) {   // x_t -> ih half (k8 0..63)
            float4 v = *(const float4*)(x + ((size_t)bglobS * Tlen + t) * HD + k4 * 4);
            cvt4s(&inb[(((k4 >> 1)) * GB + bb) * 8 + (k4 & 1) * 4], v);
        } else {        // h1_{t-1} -> hh half (k8 64..127)
            if (t == 0) {
                float4 v = *(const float4*)(h0in + (size_t)(Bsz + bglobS) * HD + k4 * 4);
                cvt4s(&inb[((64 + (k4 >> 1)) * GB + bb) * 8 + (k4 & 1) * 4], v);
            } else {
                if (tid == 0) spin_ge8(cg1 + t - 1);
                __syncthreads();
                ull v = ring_ld(H1r + ((size_t)((t - 1) & (RING - 1)) * Bsz + bglobS) * HD + k4 * 4);
                *(ull*)&inb[((64 + (k4 >> 1)) * GB + bb) * 8 + (k4 & 1) * 4] = v;
            }
        }
        __syncthreads();

        // ---------- phase A compute ----------
        {
            const uint4* Ip = (const uint4*)inb;
            const uint4* wr = wreg + (l ? 8 : 0);
            const int kbase = l ? 64 : 0;
#pragma unroll
            for (int i = 0; i < 4; ++i) {
                const int k8 = kbase + kq + 16 * i;
                const uint4 w0 = wr[i * 2 + 0], w1 = wr[i * 2 + 1];
#pragma unroll
                for (int b = 0; b < 4; ++b) {
                    const uint4 h = Ip[k8 * GB + b];
                    acc[0][b] = dot2acc(w0.x, h.x, acc[0][b]);
                    acc[0][b] = dot2acc(w0.y, h.y, acc[0][b]);
                    acc[0][b] = dot2acc(w0.z, h.z, acc[0][b]);
                    acc[0][b] = dot2acc(w0.w, h.w, acc[0][b]);
                    acc[1][b] = dot2acc(w1.x, h.x, acc[1][b]);
                    acc[1][b] = dot2acc(w1.y, h.y, acc[1][b]);
                    acc[1][b] = dot2acc(w1.z, h.z, acc[1][b]);
                    acc[1][b] = dot2acc(w1.w, h.w, acc[1][b]);
                }
            }
        }

        // ---------- phase B poll + staging (late input) ----------
        if (l == 0) {   // h0_{t-1} -> hh half
            if (tid == 0) {
                if (t > 0)     spin_ge8(cg0 + t - 1);
                if (t >= RING) spin_ge8(cg1 + t - RING);   // ring backpressure
            }
            __syncthreads();
            if (t == 0) {
                float4 v = *(const float4*)(h0in + (size_t)bglobS * HD + k4 * 4);
                cvt4s(&inb[((64 + (k4 >> 1)) * GB + bb) * 8 + (k4 & 1) * 4], v);
            } else {
                ull v = ring_ld(H0r + ((size_t)((t - 1) & (RING - 1)) * Bsz + bglobS) * HD + k4 * 4);
                *(ull*)&inb[((64 + (k4 >> 1)) * GB + bb) * 8 + (k4 & 1) * 4] = v;
            }
        } else {        // h0_t -> ih half
            if (tid == 0) spin_ge8(cg0 + t);
            __syncthreads();
            ull v = ring_ld(H0r + ((size_t)slot * Bsz + bglobS) * HD + k4 * 4);
            *(ull*)&inb[((k4 >> 1) * GB + bb) * 8 + (k4 & 1) * 4] = v;
        }
        __syncthreads();

        // ---------- phase B compute (other half) ----------
        {
            const uint4* Ip = (const uint4*)inb;
            const uint4* wr = wreg + (l ? 0 : 8);
            const int kbase = l ? 0 : 64;
#pragma unroll
            for (int i = 0; i < 4; ++i) {
                const int k8 = kbase + kq + 16 * i;
                const uint4 w0 = wr[i * 2 + 0], w1 = wr[i * 2 + 1];
#pragma unroll
                for (int b = 0; b < 4; ++b) {
                    const uint4 h = Ip[k8 * GB + b];
                    acc[0][b] = dot2acc(w0.x, h.x, acc[0][b]);
                    acc[0][b] = dot2acc(w0.y, h.y, acc[0][b]);
                    acc[0][b] = dot2acc(w0.z, h.z, acc[0][b]);
                    acc[0][b] = dot2acc(w0.w, h.w, acc[0][b]);
                    acc[1][b] = dot2acc(w1.x, h.x, acc[1][b]);
                    acc[1][b] = dot2acc(w1.y, h.y, acc[1][b]);
                    acc[1][b] = dot2acc(w1.z, h.z, acc[1][b]);
                    acc[1][b] = dot2acc(w1.w, h.w, acc[1][b]);
                }
            }
        }

        // ---------- reduce across kq via LDS ----------
#pragma unroll
        for (int ri = 0; ri < 2; ++ri)
#pragma unroll
            for (int b = 0; b < 4; ++b)
                part[(size_t)(b * 64 + rq + 16 * (2 * rh + ri)) * 17 + kq] = acc[ri][b];
        __syncthreads();

        if (tid < 256) {
            float s = bias;
#pragma unroll
            for (int k2 = 0; k2 < 16; ++k2) s += part[(size_t)tid * 17 + k2];
            const float hv = tanhf(s);
            hout[tid] = (_Float16)hv;
            const int rowg = rb * 64 + (tid & 63);
            const int bo = g * GB + (tid >> 6);
            if (l == 1) out[((size_t)bo * Tlen + t) * HD + rowg] = hv;
            if (t == Tlen - 1)
                out[(size_t)Bsz * Tlen * HD + ((size_t)l * Bsz + bo) * HD + rowg] = hv;
        }
        __syncthreads();

        // ---------- publish 512B h-slice + flag ----------
        if (tid < 64) {
            ull v = *(const ull*)(hout + (tid >> 4) * 64 + (tid & 15) * 4);
            ring_st(ringo + ((size_t)slot * Bsz + g * GB + (tid >> 4)) * HD + rb * 64 + (tid & 15) * 4, v);
        }
        asm volatile("s_waitcnt vmcnt(0)" ::: "memory");  // hand-rolled release
        if (tid == 0)
            __hip_atomic_fetch_add(cown + t, 1u, __ATOMIC_RELAXED, __HIP_MEMORY_SCOPE_AGENT);
    }
}

extern "C" void kernel_launch(void* const* d_in, const int* in_sizes, int n_in,
                              void* d_out, int out_size, void* d_ws, size_t ws_size,
                              hipStream_t stream) {
    const float* x   = (const float*)d_in[0];
    const float* h0  = (const float*)d_in[1];
    const float* Wih = (const float*)d_in[2];
    const float* bih = (const float*)d_in[3];
    const float* Whh = (const float*)d_in[4];
    const float* bhh = (const float*)d_in[5];
    float* out = (float*)d_out;

    char* ws = (char*)d_ws;
    unsigned* c0  = (unsigned*)ws;                         // 32 KB
    unsigned* c1  = (unsigned*)(ws + 32768);               // 32 KB
    _Float16* H0r = (_Float16*)(ws + 65536);               // 1 MB ring
    _Float16* H1r = (_Float16*)(ws + 65536 + (1u << 20));  // 1 MB ring

    (void)hipMemsetAsync(ws, 0, 65536, stream);

    void* args[] = { (void*)&x, (void*)&h0, (void*)&Wih, (void*)&bih, (void*)&Whh,
                     (void*)&bhh, (void*)&H0r, (void*)&H1r, (void*)&c0, (void*)&c1,
                     (void*)&out };
    (void)hipLaunchCooperativeKernel((const void*)rnn_chain, dim3(256), dim3(512),
                                     args, 0, stream);
}

// Round 5
// 1684.733 us; speedup vs baseline: 18.7805x; 1.5784x over previous
//
#include <hip/hip_runtime.h>
#include <hip/hip_fp16.h>

#define HD 512
#define Bsz 64
#define Tlen 512
#define GB 4
#define RING 16

typedef _Float16 h2v __attribute__((ext_vector_type(2)));
typedef unsigned u32x4 __attribute__((ext_vector_type(4)));
typedef unsigned long long ull;

__device__ __forceinline__ float dot2acc(unsigned a, unsigned b, float c) {
    return __builtin_amdgcn_fdot2(__builtin_bit_cast(h2v, a),
                                  __builtin_bit_cast(h2v, b), c, false);
}

// 16B coherent (MALL) transfers — sc0 sc1, no cache-wide maintenance.
// ext_vector_type (not HIP's struct uint4) is required for the 'v' constraint.
__device__ __forceinline__ u32x4 mall_ld16(const void* p) {
    u32x4 r;
    asm volatile("global_load_dwordx4 %0, %1, off sc0 sc1\n\ts_waitcnt vmcnt(0)"
                 : "=v"(r) : "v"(p) : "memory");
    return r;
}
__device__ __forceinline__ void mall_st16(void* p, u32x4 v) {
    asm volatile("global_store_dwordx4 %0, %1, off sc0 sc1"
                 :: "v"(p), "v"(v) : "memory");
}

// wave-0 combined poll: lanes 0..7 poll a[0..7], lanes 8..15 poll b[0..7].
__device__ __forceinline__ void poll2(unsigned* a, unsigned* b) {
    const int ln = threadIdx.x;  // caller guarantees < 64
    unsigned* fp = nullptr;
    if (ln < 8)       { if (a) fp = a + ln; }
    else if (ln < 16) { if (b) fp = b + (ln - 8); }
    for (;;) {
        unsigned v = fp ? __hip_atomic_load(fp, __ATOMIC_RELAXED, __HIP_MEMORY_SCOPE_AGENT) : 1u;
        if (!__any((int)(v != 1u))) break;
        __builtin_amdgcn_s_sleep(1);
    }
}

__device__ __forceinline__ void cvt4s(_Float16* d, float4 v) {
    union { ull u; _Float16 h[4]; } t;
    t.h[0] = (_Float16)v.x; t.h[1] = (_Float16)v.y;
    t.h[2] = (_Float16)v.z; t.h[3] = (_Float16)v.w;
    *(ull*)d = t.u;
}

__device__ __forceinline__ void gemm4(const u32x4* __restrict__ Ip, const u32x4* wr,
                                      int kq, int kbase, float acc[2][4]) {
#pragma unroll
    for (int i = 0; i < 4; ++i) {
        const int k8 = kbase + kq + 16 * i;
        const u32x4 w0 = wr[i * 2 + 0], w1 = wr[i * 2 + 1];
#pragma unroll
        for (int b = 0; b < 4; ++b) {
            const u32x4 h = Ip[k8 * 4 + b];
#pragma unroll
            for (int e = 0; e < 4; ++e) {
                acc[0][b] = dot2acc(w0[e], h[e], acc[0][b]);
                acc[1][b] = dot2acc(w1[e], h[e], acc[1][b]);
            }
        }
    }
}

// Grid: 256 WGs = (slice sl 0..15) x (group g 0..15); sl = l*8 + rb.
// WG owns rows [rb*64, rb*64+64) of layer l, batches [g*4, g*4+4).
// Weights in registers: thread (rh,kq,rq) holds rows rq+16*(2rh+ri), k8=kq+16i.
__global__ __launch_bounds__(512, 1) void rnn_chain(
    const float* __restrict__ x, const float* __restrict__ h0in,
    const float* __restrict__ Wih, const float* __restrict__ bih,
    const float* __restrict__ Whh, const float* __restrict__ bhh,
    _Float16* __restrict__ H0r, _Float16* __restrict__ H1r,
    unsigned* f0, unsigned* f1, float* __restrict__ out)
{
    __shared__ _Float16 inb[128 * GB * 8] __attribute__((aligned(16)));
    __shared__ float    part[256 * 17];
    __shared__ _Float16 hout[256] __attribute__((aligned(16)));

    const int bid = blockIdx.x;
    const int g   = bid & 15;
    const int sl  = bid >> 4;
    const int l   = sl >> 3;
    const int rb  = sl & 7;
    const int tid = threadIdx.x;
    const int rh = tid >> 8, kq = (tid >> 4) & 15, rq = tid & 15;

    u32x4 wreg[16];
    {
        const float* WI = Wih + (size_t)l * HD * HD;
        const float* WH = Whh + (size_t)l * HD * HD;
#pragma unroll
        for (int ph = 0; ph < 2; ++ph) {
            const float* W = ph ? WH : WI;
#pragma unroll
            for (int i = 0; i < 4; ++i)
#pragma unroll
                for (int ri = 0; ri < 2; ++ri) {
                    const int row = rb * 64 + rq + 16 * (2 * rh + ri);
                    const float* p = W + (size_t)row * HD + (kq + 16 * i) * 8;
                    union { u32x4 u; _Float16 h[8]; } v;
#pragma unroll
                    for (int e = 0; e < 8; ++e) v.h[e] = (_Float16)p[e];
                    wreg[ph * 8 + i * 2 + ri] = v.u;
                }
        }
    }

    float bias = 0.f;
    if (tid < 256) {
        const int rowg = rb * 64 + (tid & 63);
        bias = bih[l * HD + rowg] + bhh[l * HD + rowg];
    }

    unsigned* fown = (l ? f1 : f0) + ((size_t)g * Tlen) * 8 + rb;
    _Float16* ringo = l ? H1r : H0r;
    const u32x4* Ip = (const u32x4*)inb;

    const int bb = tid >> 7;      // l=0 x-staging: batch-in-group
    const int k4 = tid & 127;     // l=0 x-staging: float4 chunk
    const int bglobS = g * GB + bb;

    float4 xreg;
    if (l == 0) xreg = *(const float4*)(x + (size_t)bglobS * Tlen * HD + k4 * 4);

    for (int t = 0; t < Tlen; ++t) {
        const int slot = t & (RING - 1);
        float acc[2][4] = {{0, 0, 0, 0}, {0, 0, 0, 0}};

        if (l == 0) {
            // ---- phase A: stage x_t (prefetched), compute ih half ----
            cvt4s(&inb[((k4 >> 1) * GB + bb) * 8 + (k4 & 1) * 4], xreg);
            __syncthreads();
            if (t + 1 < Tlen)
                xreg = *(const float4*)(x + ((size_t)bglobS * Tlen + t + 1) * HD + k4 * 4);
            gemm4(Ip, wreg, kq, 0, acc);
            // ---- poll peers' h0_{t-1} + ring backpressure, one loop ----
            if (tid < 64)
                poll2((t > 0)     ? f0 + ((size_t)g * Tlen + (t - 1)) * 8 : nullptr,
                      (t >= RING) ? f1 + ((size_t)g * Tlen + (t - RING)) * 8 : nullptr);
            __syncthreads();
            // ---- stage hh input ----
            if (t == 0) {
                if (tid < 256) {
                    int b2 = tid >> 6, k8 = tid & 63;
                    const float* src = h0in + (size_t)(g * GB + b2) * HD + k8 * 8;
                    cvt4s(&inb[((64 + k8) * GB + b2) * 8],     *(const float4*)src);
                    cvt4s(&inb[((64 + k8) * GB + b2) * 8 + 4], *(const float4*)(src + 4));
                }
            } else if (tid < 256) {
                int b2 = tid >> 6, k8 = tid & 63;
                u32x4 v = mall_ld16(H0r + ((size_t)((t - 1) & (RING - 1)) * Bsz + g * GB + b2) * HD + k8 * 8);
                *(u32x4*)&inb[((64 + k8) * GB + b2) * 8] = v;
            }
            __syncthreads();
            gemm4(Ip, wreg + 8, kq, 64, acc);
        } else {
            // ---- layer 1, fused: poll h0_t + peers' h1_{t-1} ----
            if (tid < 64)
                poll2(f0 + ((size_t)g * Tlen + t) * 8,
                      (t > 0) ? f1 + ((size_t)g * Tlen + (t - 1)) * 8 : nullptr);
            __syncthreads();
            if (tid < 256) {
                int b2 = tid >> 6, k8 = tid & 63;
                u32x4 v = mall_ld16(H0r + ((size_t)slot * Bsz + g * GB + b2) * HD + k8 * 8);
                *(u32x4*)&inb[(k8 * GB + b2) * 8] = v;
            } else if (t == 0) {
                int t2 = tid - 256; int b2 = t2 >> 6, k8 = t2 & 63;
                const float* src = h0in + (size_t)(Bsz + g * GB + b2) * HD + k8 * 8;
                cvt4s(&inb[((64 + k8) * GB + b2) * 8],     *(const float4*)src);
                cvt4s(&inb[((64 + k8) * GB + b2) * 8 + 4], *(const float4*)(src + 4));
            } else {
                int t2 = tid - 256; int b2 = t2 >> 6, k8 = t2 & 63;
                u32x4 v = mall_ld16(H1r + ((size_t)((t - 1) & (RING - 1)) * Bsz + g * GB + b2) * HD + k8 * 8);
                *(u32x4*)&inb[((64 + k8) * GB + b2) * 8] = v;
            }
            __syncthreads();
            gemm4(Ip, wreg, kq, 0, acc);
            gemm4(Ip, wreg + 8, kq, 64, acc);
        }

        // ---- reduce across kq, tanh, outputs ----
#pragma unroll
        for (int ri = 0; ri < 2; ++ri)
#pragma unroll
            for (int b = 0; b < 4; ++b)
                part[(size_t)(b * 64 + rq + 16 * (2 * rh + ri)) * 17 + kq] = acc[ri][b];
        __syncthreads();
        if (tid < 256) {
            float s = bias;
#pragma unroll
            for (int k2 = 0; k2 < 16; ++k2) s += part[(size_t)tid * 17 + k2];
            const float hv = tanhf(s);
            hout[tid] = (_Float16)hv;
            const int rowg = rb * 64 + (tid & 63);
            const int bo = g * GB + (tid >> 6);
            if (l == 1) out[((size_t)bo * Tlen + t) * HD + rowg] = hv;
            if (t == Tlen - 1)
                out[(size_t)Bsz * Tlen * HD + ((size_t)l * Bsz + bo) * HD + rowg] = hv;
        }
        __syncthreads();

        // ---- publish 512B h-slice (32 lanes x 16B) + per-producer flag ----
        if (tid < 32) {
            u32x4 v = *(const u32x4*)&hout[(tid >> 3) * 64 + (tid & 7) * 8];
            mall_st16(ringo + ((size_t)slot * Bsz + g * GB + (tid >> 3)) * HD + rb * 64 + (tid & 7) * 8, v);
        }
        if (tid < 64) {
            asm volatile("s_waitcnt vmcnt(0)" ::: "memory");  // drain ring stores
            if (tid == 0)
                __hip_atomic_store(fown + (size_t)t * 8, 1u,
                                   __ATOMIC_RELAXED, __HIP_MEMORY_SCOPE_AGENT);
        }
    }
}

extern "C" void kernel_launch(void* const* d_in, const int* in_sizes, int n_in,
                              void* d_out, int out_size, void* d_ws, size_t ws_size,
                              hipStream_t stream) {
    const float* x   = (const float*)d_in[0];
    const float* h0  = (const float*)d_in[1];
    const float* Wih = (const float*)d_in[2];
    const float* bih = (const float*)d_in[3];
    const float* Whh = (const float*)d_in[4];
    const float* bhh = (const float*)d_in[5];
    float* out = (float*)d_out;

    char* ws = (char*)d_ws;
    unsigned* f0  = (unsigned*)ws;                          // 256 KB (16*512*8 words)
    unsigned* f1  = (unsigned*)(ws + (256u << 10));         // 256 KB
    _Float16* H0r = (_Float16*)(ws + (512u << 10));         // 1 MB ring
    _Float16* H1r = (_Float16*)(ws + (512u << 10) + (1u << 20));

    (void)hipMemsetAsync(ws, 0, 512u << 10, stream);        // zero flags

    void* args[] = { (void*)&x, (void*)&h0, (void*)&Wih, (void*)&bih, (void*)&Whh,
                     (void*)&bhh, (void*)&H0r, (void*)&H1r, (void*)&f0, (void*)&f1,
                     (void*)&out };
    (void)hipLaunchCooperativeKernel((const void*)rnn_chain, dim3(256), dim3(512),
                                     args, 0, stream);
}